// Round 3
// baseline (20025.890 us; speedup 1.0000x reference)
//
#include <hip/hip_runtime.h>
#include <hip/hip_bf16.h>

// ---------------------------------------------------------------------------
// Attention LSTM decoder (LAS-style), 300 sequential steps.
// Design: 4 kernels per step (kernel boundary = device-wide sync):
//   k_lstm1: gates1 = [ce|ctx|h1_prev] @ W1^T (+bias) -> h1,c1   (256 WGs x256)
//   k_lstm2: gates2 = [h1|h2_prev] @ W2^T -> h2,c2               (64 WGs x256)
//   k_attn : per 8-timestep slice: energy, local softmax partial,
//            partial ctx (flash-style)                           (250 WGs x512)
//   k_fin  : combine partials -> ctx, pred logits -> d_out       (64 WGs x256)
// All fp32. State double-buffered across steps where cross-WG RAW exists.
// ---------------------------------------------------------------------------

constexpr int V_  = 35;
constexpr int E_  = 256;
constexpr int H_  = 512;   // lstm1 hidden
constexpr int KS_ = 128;   // key size / lstm2 hidden
constexpr int VS_ = 128;   // value size
constexpr int NB_ = 64;    // batch
constexpr int TT_ = 2000;  // enc time
constexpr int LL_ = 300;   // dec steps
constexpr int START_ = 33;

__device__ __forceinline__ void fma4(float4& a, const float4 w, const float4 x) {
  a.x = fmaf(w.x, x.x, a.x); a.y = fmaf(w.y, x.y, a.y);
  a.z = fmaf(w.z, x.z, a.z); a.w = fmaf(w.w, x.w, a.w);
}
__device__ __forceinline__ float hsum4(const float4 a) {
  return (a.x + a.y) + (a.z + a.w);
}
__device__ __forceinline__ float sigm(float x) { return 1.0f / (1.0f + expf(-x)); }

// zero the state region: h1buf(2x64x512) c1(64x512) h2buf(2x64x128) c2 ctx
// = 131072 floats = 128 blocks * 256 thr * 1 float4
__global__ void k_zero(float* __restrict__ ws) {
  int i = blockIdx.x * 256 + threadIdx.x;
  *(float4*)&ws[(size_t)i * 4] = make_float4(0.f, 0.f, 0.f, 0.f);
}

// ---------------- LSTM1 ----------------
// grid 256 = (mtile 0..127) x (nhalf 0..1). WG owns 4 hidden units (16 gate
// rows: slot s = g*4+du <-> global row g*512+u0+du) x 32 batch rows.
// K=896 in 7 chunks of 128. Register tile 4r x 8n, ksplit 16.
__global__ __launch_bounds__(256, 1) void k_lstm1(
    const float* __restrict__ emb, const int* __restrict__ text,
    const float* __restrict__ Wih1, const float* __restrict__ Whh1,
    const float* __restrict__ bih1, const float* __restrict__ bhh1,
    const float* __restrict__ ctx, float* __restrict__ h1buf,
    float* __restrict__ c1, int t) {
  __shared__ __align__(16) float Wc[16 * 132];
  __shared__ __align__(16) float Xs[32 * 132];
  __shared__ float pp[16 * 520];
  __shared__ float gbuf[512];
  __shared__ float bias[16];

  const int tid = threadIdx.x;
  const int mtile = blockIdx.x >> 1, nhalf = blockIdx.x & 1;
  const int u0 = mtile * 4;
  const int nbase = nhalf * 32;
  const float* __restrict__ h1in = h1buf + (t & 1) * (NB_ * H_);
  float* __restrict__ h1out = h1buf + ((t & 1) ^ 1) * (NB_ * H_);

  if (tid < 16) {
    int g = tid >> 2, du = tid & 3;
    int grow = g * H_ + u0 + du;
    bias[tid] = bih1[grow] + bhh1[grow];
  }

  const int ng = tid & 3, rg = (tid >> 2) & 3, ks = tid >> 4;  // 4 x 4 x 16
  float4 acc[4][8];
#pragma unroll
  for (int j = 0; j < 4; ++j)
#pragma unroll
    for (int i = 0; i < 8; ++i) acc[j][i] = make_float4(0.f, 0.f, 0.f, 0.f);

  for (int c = 0; c < 7; ++c) {
    __syncthreads();
    // stage W chunk: 512 float4
#pragma unroll
    for (int i = 0; i < 2; ++i) {
      int f4 = i * 256 + tid;
      int rl = f4 >> 5, kq = f4 & 31;
      int g = rl >> 2, du = rl & 3;
      int grow = g * H_ + u0 + du;
      int k = c * 128 + kq * 4;
      float4 v;
      if (k < 384) v = *(const float4*)&Wih1[grow * 384 + k];
      else         v = *(const float4*)&Whh1[grow * 512 + (k - 384)];
      *(float4*)&Wc[rl * 132 + kq * 4] = v;
    }
    // stage X chunk: 1024 float4. X = [ce(256) | ctx(128) | h1_prev(512)]
#pragma unroll
    for (int i = 0; i < 4; ++i) {
      int f4 = i * 256 + tid;
      int nl = f4 >> 5, kq = f4 & 31;
      int n = nbase + nl;
      int k = c * 128 + kq * 4;
      float4 v;
      if (c < 2) {
        int tok = (t == 0) ? START_ : text[n * LL_ + t - 1];
        v = *(const float4*)&emb[tok * E_ + k];
      } else if (c == 2) {
        v = *(const float4*)&ctx[n * VS_ + (k - 256)];
      } else {
        v = *(const float4*)&h1in[n * H_ + (k - 384)];
      }
      *(float4*)&Xs[nl * 132 + kq * 4] = v;
    }
    __syncthreads();
#pragma unroll
    for (int it = 0; it < 2; ++it) {
      int kl = (it * 16 + ks) * 4;
      float4 w[4], x[8];
#pragma unroll
      for (int j = 0; j < 4; ++j) w[j] = *(const float4*)&Wc[(rg * 4 + j) * 132 + kl];
#pragma unroll
      for (int i = 0; i < 8; ++i) x[i] = *(const float4*)&Xs[(ng + 4 * i) * 132 + kl];
#pragma unroll
      for (int j = 0; j < 4; ++j)
#pragma unroll
        for (int i = 0; i < 8; ++i) fma4(acc[j][i], w[j], x[i]);
    }
  }
  // ksplit partials
#pragma unroll
  for (int j = 0; j < 4; ++j)
#pragma unroll
    for (int i = 0; i < 8; ++i)
      pp[ks * 520 + (rg * 4 + j) * 32 + ng + 4 * i] = hsum4(acc[j][i]);
  __syncthreads();
#pragma unroll
  for (int rep = 0; rep < 2; ++rep) {
    int o = rep * 256 + tid;
    float s = 0.f;
#pragma unroll
    for (int kk = 0; kk < 16; ++kk) s += pp[kk * 520 + o];
    gbuf[o] = s + bias[o >> 5];
  }
  __syncthreads();
  if (tid < 128) {
    int du = tid & 3, nl = tid >> 2;
    int n = nbase + nl, u = u0 + du;
    float ig = gbuf[(0 * 4 + du) * 32 + nl];
    float fg = gbuf[(1 * 4 + du) * 32 + nl];
    float gg = gbuf[(2 * 4 + du) * 32 + nl];
    float og = gbuf[(3 * 4 + du) * 32 + nl];
    float cn = sigm(fg) * c1[n * H_ + u] + sigm(ig) * tanhf(gg);
    c1[n * H_ + u] = cn;
    h1out[n * H_ + u] = sigm(og) * tanhf(cn);
  }
}

// ---------------- LSTM2 ----------------
// grid 64 = (mtile 0..31) x (nhalf). WG: 4 units (rows g*128+u0+du) x 32 n.
// K=640 in 5 chunks: c<4 -> h1_t, c==4 -> h2_prev.
__global__ __launch_bounds__(256, 1) void k_lstm2(
    const float* __restrict__ Wih2, const float* __restrict__ Whh2,
    const float* __restrict__ bih2, const float* __restrict__ bhh2,
    const float* __restrict__ h1buf, float* __restrict__ h2buf,
    float* __restrict__ c2, int t) {
  __shared__ __align__(16) float Wc[16 * 132];
  __shared__ __align__(16) float Xs[32 * 132];
  __shared__ float pp[16 * 520];
  __shared__ float gbuf[512];
  __shared__ float bias[16];

  const int tid = threadIdx.x;
  const int mtile = blockIdx.x >> 1, nhalf = blockIdx.x & 1;
  const int u0 = mtile * 4;
  const int nbase = nhalf * 32;
  const float* __restrict__ h1t = h1buf + ((t & 1) ^ 1) * (NB_ * H_);
  const float* __restrict__ h2p = h2buf + (t & 1) * (NB_ * KS_);
  float* __restrict__ h2o = h2buf + ((t & 1) ^ 1) * (NB_ * KS_);

  if (tid < 16) {
    int g = tid >> 2, du = tid & 3;
    int grow = g * KS_ + u0 + du;
    bias[tid] = bih2[grow] + bhh2[grow];
  }

  const int ng = tid & 3, rg = (tid >> 2) & 3, ks = tid >> 4;
  float4 acc[4][8];
#pragma unroll
  for (int j = 0; j < 4; ++j)
#pragma unroll
    for (int i = 0; i < 8; ++i) acc[j][i] = make_float4(0.f, 0.f, 0.f, 0.f);

  for (int c = 0; c < 5; ++c) {
    __syncthreads();
#pragma unroll
    for (int i = 0; i < 2; ++i) {
      int f4 = i * 256 + tid;
      int rl = f4 >> 5, kq = f4 & 31;
      int g = rl >> 2, du = rl & 3;
      int grow = g * KS_ + u0 + du;
      int k = c * 128 + kq * 4;
      float4 v;
      if (k < 512) v = *(const float4*)&Wih2[grow * 512 + k];
      else         v = *(const float4*)&Whh2[grow * 128 + (k - 512)];
      *(float4*)&Wc[rl * 132 + kq * 4] = v;
    }
#pragma unroll
    for (int i = 0; i < 4; ++i) {
      int f4 = i * 256 + tid;
      int nl = f4 >> 5, kq = f4 & 31;
      int n = nbase + nl;
      int k = c * 128 + kq * 4;
      float4 v;
      if (c < 4) v = *(const float4*)&h1t[n * H_ + k];
      else       v = *(const float4*)&h2p[n * KS_ + (k - 512)];
      *(float4*)&Xs[nl * 132 + kq * 4] = v;
    }
    __syncthreads();
#pragma unroll
    for (int it = 0; it < 2; ++it) {
      int kl = (it * 16 + ks) * 4;
      float4 w[4], x[8];
#pragma unroll
      for (int j = 0; j < 4; ++j) w[j] = *(const float4*)&Wc[(rg * 4 + j) * 132 + kl];
#pragma unroll
      for (int i = 0; i < 8; ++i) x[i] = *(const float4*)&Xs[(ng + 4 * i) * 132 + kl];
#pragma unroll
      for (int j = 0; j < 4; ++j)
#pragma unroll
        for (int i = 0; i < 8; ++i) fma4(acc[j][i], w[j], x[i]);
    }
  }
#pragma unroll
  for (int j = 0; j < 4; ++j)
#pragma unroll
    for (int i = 0; i < 8; ++i)
      pp[ks * 520 + (rg * 4 + j) * 32 + ng + 4 * i] = hsum4(acc[j][i]);
  __syncthreads();
#pragma unroll
  for (int rep = 0; rep < 2; ++rep) {
    int o = rep * 256 + tid;
    float s = 0.f;
#pragma unroll
    for (int kk = 0; kk < 16; ++kk) s += pp[kk * 520 + o];
    gbuf[o] = s + bias[o >> 5];
  }
  __syncthreads();
  if (tid < 128) {
    int du = tid & 3, nl = tid >> 2;
    int n = nbase + nl, u = u0 + du;
    float ig = gbuf[(0 * 4 + du) * 32 + nl];
    float fg = gbuf[(1 * 4 + du) * 32 + nl];
    float gg = gbuf[(2 * 4 + du) * 32 + nl];
    float og = gbuf[(3 * 4 + du) * 32 + nl];
    float cn = sigm(fg) * c2[n * KS_ + u] + sigm(ig) * tanhf(gg);
    c2[n * KS_ + u] = cn;
    h2o[n * KS_ + u] = sigm(og) * tanhf(cn);
  }
}

// ---------------- attention slice partials ----------------
// grid 250 x 512 threads (8 waves -> 2 waves/SIMD for L3 latency hiding).
// WG s owns timesteps [8s, 8s+8) for all 64 batch rows.
// energy: thread (n, jp) does one key row. pctx: thread (n, vq) owns 16 dims.
// Writes pm[n][s] (slice max), ps[n][s] (slice expsum), pctx[s][n][128].
__global__ __launch_bounds__(512, 1) void k_attn(
    const float* __restrict__ key, const float* __restrict__ values,
    const int* __restrict__ lens, const float* __restrict__ h2buf,
    float* __restrict__ pm, float* __restrict__ ps, float* __restrict__ pctx,
    int t) {
  __shared__ __align__(16) float h2s[64 * 132];
  __shared__ float es[64 * 9];
  const int tid = threadIdx.x;
  const int s = blockIdx.x;
  const int t0 = s * 8;
  const float* __restrict__ h2 = h2buf + ((t & 1) ^ 1) * (NB_ * KS_);

#pragma unroll
  for (int i = 0; i < 4; ++i) {
    int f4 = i * 512 + tid;
    int n = f4 >> 5, q = f4 & 31;
    *(float4*)&h2s[n * 132 + q * 4] = *(const float4*)&h2[n * KS_ + q * 4];
  }
  __syncthreads();
  {  // energies: thread (n, jp) does row t0+jp
    int n = tid >> 3, jp = tid & 7;
    const float* kr = key + ((size_t)n * TT_ + t0 + jp) * KS_;
    float4 a0 = make_float4(0.f, 0.f, 0.f, 0.f);
#pragma unroll 8
    for (int q = 0; q < 32; ++q) {
      float4 hv = *(const float4*)&h2s[n * 132 + q * 4];
      fma4(a0, *(const float4*)&kr[q * 4], hv);
    }
    float e0 = hsum4(a0);
    if (t0 + jp >= lens[n]) e0 = -1e9f;
    es[n * 9 + jp] = e0;
  }
  __syncthreads();
  if (tid < 64) {  // per-row local softmax partials
    int n = tid;
    float m = -1e30f;
#pragma unroll
    for (int j = 0; j < 8; ++j) m = fmaxf(m, es[n * 9 + j]);
    float ssum = 0.f;
#pragma unroll
    for (int j = 0; j < 8; ++j) {
      float p = expf(es[n * 9 + j] - m);
      es[n * 9 + j] = p;
      ssum += p;
    }
    pm[n * 256 + s] = m;
    ps[n * 256 + s] = ssum;
  }
  __syncthreads();
  {  // partial ctx: thread (n, vq) owns v in [16vq, 16vq+16)
    int n = tid >> 3, vq = tid & 7;
    float4 a[4];
#pragma unroll
    for (int q = 0; q < 4; ++q) a[q] = make_float4(0.f, 0.f, 0.f, 0.f);
    for (int j = 0; j < 8; ++j) {
      float p = es[n * 9 + j];
      const float* vr = values + ((size_t)n * TT_ + t0 + j) * VS_ + vq * 16;
#pragma unroll
      for (int q = 0; q < 4; ++q) {
        float4 vv = *(const float4*)&vr[q * 4];
        a[q].x = fmaf(p, vv.x, a[q].x); a[q].y = fmaf(p, vv.y, a[q].y);
        a[q].z = fmaf(p, vv.z, a[q].z); a[q].w = fmaf(p, vv.w, a[q].w);
      }
    }
    float* dst = pctx + ((size_t)s * 64 + n) * 128 + vq * 16;
#pragma unroll
    for (int q = 0; q < 4; ++q) *(float4*)&dst[q * 4] = a[q];
  }
}

// ---------------- finalize: combine partials, ctx, pred ----------------
// grid 64 (one WG per batch row).
__global__ __launch_bounds__(256, 1) void k_fin(
    const float* __restrict__ pm, const float* __restrict__ ps,
    const float* __restrict__ pctx, const float* __restrict__ h2buf,
    const float* __restrict__ emb, const float* __restrict__ bout,
    float* __restrict__ ctx, float* __restrict__ out, int t) {
  __shared__ float red[256];
  __shared__ float ews[256];
  __shared__ float cbuf[256];
  __shared__ float cat[256];
  const int tid = threadIdx.x;
  const int n = blockIdx.x;
  const float* __restrict__ h2 = h2buf + ((t & 1) ^ 1) * (NB_ * KS_);

  float m = -1e30f;
  if (tid < 250) m = pm[n * 256 + tid];
  red[tid] = m;
  __syncthreads();
  for (int w = 128; w > 0; w >>= 1) {
    if (tid < w) red[tid] = fmaxf(red[tid], red[tid + w]);
    __syncthreads();
  }
  float M = red[0];
  __syncthreads();
  float wv = 0.f;
  if (tid < 250) {
    float e = expf(m - M);
    ews[tid] = e;
    wv = e * ps[n * 256 + tid];
  } else {
    ews[tid] = 0.f;
  }
  red[tid] = wv;
  __syncthreads();
  for (int w = 128; w > 0; w >>= 1) {
    if (tid < w) red[tid] += red[tid + w];
    __syncthreads();
  }
  float S = red[0];
  {  // ctx accumulate: thread (v = tid&127, sh = tid>>7) over 125 slices
    int v = tid & 127, sh = tid >> 7;
    float a = 0.f;
    for (int i = 0; i < 125; ++i) {
      int sl = sh * 125 + i;
      a = fmaf(ews[sl], pctx[((size_t)sl * 64 + n) * 128 + v], a);
    }
    cbuf[sh * 128 + v] = a;
  }
  __syncthreads();
  if (tid < 128) {
    float cv = (cbuf[tid] + cbuf[128 + tid]) / S;
    ctx[n * 128 + tid] = cv;
    cat[128 + tid] = cv;
    cat[tid] = h2[n * KS_ + tid];
  }
  __syncthreads();
  if (tid < V_) {  // tied-weight pred: logits = [h2|ctx] @ emb^T + b_out
    float a = bout[tid];
    const float* er = emb + tid * E_;
#pragma unroll 8
    for (int q = 0; q < 64; ++q) {
      float4 ev = *(const float4*)&er[q * 4];
      a = fmaf(ev.x, cat[q * 4 + 0], a);
      a = fmaf(ev.y, cat[q * 4 + 1], a);
      a = fmaf(ev.z, cat[q * 4 + 2], a);
      a = fmaf(ev.w, cat[q * 4 + 3], a);
    }
    out[((size_t)n * LL_ + t) * V_ + tid] = a;
  }
}

extern "C" void kernel_launch(void* const* d_in, const int* in_sizes, int n_in,
                              void* d_out, int out_size, void* d_ws,
                              size_t ws_size, hipStream_t stream) {
  const float* key    = (const float*)d_in[0];
  const float* values = (const float*)d_in[1];
  const int*   lens   = (const int*)d_in[2];
  const int*   text   = (const int*)d_in[3];
  const float* emb    = (const float*)d_in[4];
  const float* Wih1   = (const float*)d_in[5];
  const float* Whh1   = (const float*)d_in[6];
  const float* bih1   = (const float*)d_in[7];
  const float* bhh1   = (const float*)d_in[8];
  const float* Wih2   = (const float*)d_in[9];
  const float* Whh2   = (const float*)d_in[10];
  const float* bih2   = (const float*)d_in[11];
  const float* bhh2   = (const float*)d_in[12];
  const float* bout   = (const float*)d_in[13];
  float* out = (float*)d_out;
  float* ws = (float*)d_ws;

  // workspace layout (floats):
  float* h1buf = ws;               // 2 * 64*512 = 65536
  float* c1    = ws + 65536;       // 32768
  float* h2buf = ws + 98304;       // 2 * 64*128 = 16384
  float* c2    = ws + 114688;      // 8192
  float* ctx   = ws + 122880;      // 8192   (state region ends at 131072)
  float* pm    = ws + 131072;      // 64*256 = 16384
  float* ps    = ws + 147456;      // 16384
  float* pctx  = ws + 163840;      // 250*64*128 = 2048000 (~8.9 MB total)

  hipLaunchKernelGGL(k_zero, dim3(128), dim3(256), 0, stream, ws);
  for (int t = 0; t < LL_; ++t) {
    hipLaunchKernelGGL(k_lstm1, dim3(256), dim3(256), 0, stream,
                       emb, text, Wih1, Whh1, bih1, bhh1, ctx, h1buf, c1, t);
    hipLaunchKernelGGL(k_lstm2, dim3(64), dim3(256), 0, stream,
                       Wih2, Whh2, bih2, bhh2, h1buf, h2buf, c2, t);
    hipLaunchKernelGGL(k_attn, dim3(250), dim3(512), 0, stream,
                       key, values, lens, h2buf, pm, ps, pctx, t);
    hipLaunchKernelGGL(k_fin, dim3(64), dim3(256), 0, stream,
                       pm, ps, pctx, h2buf, emb, bout, ctx, out, t);
  }
}

// Round 5
// 19298.486 us; speedup vs baseline: 1.0377x; 1.0377x over previous
//
#include <hip/hip_runtime.h>
#include <hip/hip_bf16.h>

// ---------------------------------------------------------------------------
// Attention LSTM decoder (LAS-style), 300 sequential steps.
// Design: 4 kernels per step (kernel boundary = device-wide sync):
//   k_lstm1: gates1 = [ce|ctx|h1_prev] @ W1^T (+bias) -> h1,c1   (256 WGs x256)
//   k_lstm2: gates2 = [h1|h2_prev] @ W2^T -> h2,c2               (64 WGs x256)
//   k_attn : per 8-timestep slice: energy, local softmax partial,
//            partial ctx (flash-style)                           (250 WGs x512)
//   k_fin  : combine partials -> ctx, pred logits -> d_out       (64 WGs x256)
// All fp32. State double-buffered across steps where cross-WG RAW exists.
// R3 delta: k_attn rewritten for wave-contiguous global loads (1 KB/instr,
// lines consumed immediately; no L1-retention dependence) + shuffle reduces.
// ---------------------------------------------------------------------------

constexpr int V_  = 35;
constexpr int E_  = 256;
constexpr int H_  = 512;   // lstm1 hidden
constexpr int KS_ = 128;   // key size / lstm2 hidden
constexpr int VS_ = 128;   // value size
constexpr int NB_ = 64;    // batch
constexpr int TT_ = 2000;  // enc time
constexpr int LL_ = 300;   // dec steps
constexpr int START_ = 33;

__device__ __forceinline__ void fma4(float4& a, const float4 w, const float4 x) {
  a.x = fmaf(w.x, x.x, a.x); a.y = fmaf(w.y, x.y, a.y);
  a.z = fmaf(w.z, x.z, a.z); a.w = fmaf(w.w, x.w, a.w);
}
__device__ __forceinline__ float hsum4(const float4 a) {
  return (a.x + a.y) + (a.z + a.w);
}
__device__ __forceinline__ float sigm(float x) { return 1.0f / (1.0f + expf(-x)); }

// zero the state region: h1buf(2x64x512) c1(64x512) h2buf(2x64x128) c2 ctx
// = 131072 floats = 128 blocks * 256 thr * 1 float4
__global__ void k_zero(float* __restrict__ ws) {
  int i = blockIdx.x * 256 + threadIdx.x;
  *(float4*)&ws[(size_t)i * 4] = make_float4(0.f, 0.f, 0.f, 0.f);
}

// ---------------- LSTM1 ----------------
// grid 256 = (mtile 0..127) x (nhalf 0..1). WG owns 4 hidden units (16 gate
// rows: slot s = g*4+du <-> global row g*512+u0+du) x 32 batch rows.
// K=896 in 7 chunks of 128. Register tile 4r x 8n, ksplit 16.
__global__ __launch_bounds__(256, 1) void k_lstm1(
    const float* __restrict__ emb, const int* __restrict__ text,
    const float* __restrict__ Wih1, const float* __restrict__ Whh1,
    const float* __restrict__ bih1, const float* __restrict__ bhh1,
    const float* __restrict__ ctx, float* __restrict__ h1buf,
    float* __restrict__ c1, int t) {
  __shared__ __align__(16) float Wc[16 * 132];
  __shared__ __align__(16) float Xs[32 * 132];
  __shared__ float pp[16 * 520];
  __shared__ float gbuf[512];
  __shared__ float bias[16];

  const int tid = threadIdx.x;
  const int mtile = blockIdx.x >> 1, nhalf = blockIdx.x & 1;
  const int u0 = mtile * 4;
  const int nbase = nhalf * 32;
  const float* __restrict__ h1in = h1buf + (t & 1) * (NB_ * H_);
  float* __restrict__ h1out = h1buf + ((t & 1) ^ 1) * (NB_ * H_);

  if (tid < 16) {
    int g = tid >> 2, du = tid & 3;
    int grow = g * H_ + u0 + du;
    bias[tid] = bih1[grow] + bhh1[grow];
  }

  const int ng = tid & 3, rg = (tid >> 2) & 3, ks = tid >> 4;  // 4 x 4 x 16
  float4 acc[4][8];
#pragma unroll
  for (int j = 0; j < 4; ++j)
#pragma unroll
    for (int i = 0; i < 8; ++i) acc[j][i] = make_float4(0.f, 0.f, 0.f, 0.f);

  for (int c = 0; c < 7; ++c) {
    __syncthreads();
    // stage W chunk: 512 float4
#pragma unroll
    for (int i = 0; i < 2; ++i) {
      int f4 = i * 256 + tid;
      int rl = f4 >> 5, kq = f4 & 31;
      int g = rl >> 2, du = rl & 3;
      int grow = g * H_ + u0 + du;
      int k = c * 128 + kq * 4;
      float4 v;
      if (k < 384) v = *(const float4*)&Wih1[grow * 384 + k];
      else         v = *(const float4*)&Whh1[grow * 512 + (k - 384)];
      *(float4*)&Wc[rl * 132 + kq * 4] = v;
    }
    // stage X chunk: 1024 float4. X = [ce(256) | ctx(128) | h1_prev(512)]
#pragma unroll
    for (int i = 0; i < 4; ++i) {
      int f4 = i * 256 + tid;
      int nl = f4 >> 5, kq = f4 & 31;
      int n = nbase + nl;
      int k = c * 128 + kq * 4;
      float4 v;
      if (c < 2) {
        int tok = (t == 0) ? START_ : text[n * LL_ + t - 1];
        v = *(const float4*)&emb[tok * E_ + k];
      } else if (c == 2) {
        v = *(const float4*)&ctx[n * VS_ + (k - 256)];
      } else {
        v = *(const float4*)&h1in[n * H_ + (k - 384)];
      }
      *(float4*)&Xs[nl * 132 + kq * 4] = v;
    }
    __syncthreads();
#pragma unroll
    for (int it = 0; it < 2; ++it) {
      int kl = (it * 16 + ks) * 4;
      float4 w[4], x[8];
#pragma unroll
      for (int j = 0; j < 4; ++j) w[j] = *(const float4*)&Wc[(rg * 4 + j) * 132 + kl];
#pragma unroll
      for (int i = 0; i < 8; ++i) x[i] = *(const float4*)&Xs[(ng + 4 * i) * 132 + kl];
#pragma unroll
      for (int j = 0; j < 4; ++j)
#pragma unroll
        for (int i = 0; i < 8; ++i) fma4(acc[j][i], w[j], x[i]);
    }
  }
  // ksplit partials
#pragma unroll
  for (int j = 0; j < 4; ++j)
#pragma unroll
    for (int i = 0; i < 8; ++i)
      pp[ks * 520 + (rg * 4 + j) * 32 + ng + 4 * i] = hsum4(acc[j][i]);
  __syncthreads();
#pragma unroll
  for (int rep = 0; rep < 2; ++rep) {
    int o = rep * 256 + tid;
    float s = 0.f;
#pragma unroll
    for (int kk = 0; kk < 16; ++kk) s += pp[kk * 520 + o];
    gbuf[o] = s + bias[o >> 5];
  }
  __syncthreads();
  if (tid < 128) {
    int du = tid & 3, nl = tid >> 2;
    int n = nbase + nl, u = u0 + du;
    float ig = gbuf[(0 * 4 + du) * 32 + nl];
    float fg = gbuf[(1 * 4 + du) * 32 + nl];
    float gg = gbuf[(2 * 4 + du) * 32 + nl];
    float og = gbuf[(3 * 4 + du) * 32 + nl];
    float cn = sigm(fg) * c1[n * H_ + u] + sigm(ig) * tanhf(gg);
    c1[n * H_ + u] = cn;
    h1out[n * H_ + u] = sigm(og) * tanhf(cn);
  }
}

// ---------------- LSTM2 ----------------
// grid 64 = (mtile 0..31) x (nhalf). WG: 4 units (rows g*128+u0+du) x 32 n.
// K=640 in 5 chunks: c<4 -> h1_t, c==4 -> h2_prev.
__global__ __launch_bounds__(256, 1) void k_lstm2(
    const float* __restrict__ Wih2, const float* __restrict__ Whh2,
    const float* __restrict__ bih2, const float* __restrict__ bhh2,
    const float* __restrict__ h1buf, float* __restrict__ h2buf,
    float* __restrict__ c2, int t) {
  __shared__ __align__(16) float Wc[16 * 132];
  __shared__ __align__(16) float Xs[32 * 132];
  __shared__ float pp[16 * 520];
  __shared__ float gbuf[512];
  __shared__ float bias[16];

  const int tid = threadIdx.x;
  const int mtile = blockIdx.x >> 1, nhalf = blockIdx.x & 1;
  const int u0 = mtile * 4;
  const int nbase = nhalf * 32;
  const float* __restrict__ h1t = h1buf + ((t & 1) ^ 1) * (NB_ * H_);
  const float* __restrict__ h2p = h2buf + (t & 1) * (NB_ * KS_);
  float* __restrict__ h2o = h2buf + ((t & 1) ^ 1) * (NB_ * KS_);

  if (tid < 16) {
    int g = tid >> 2, du = tid & 3;
    int grow = g * KS_ + u0 + du;
    bias[tid] = bih2[grow] + bhh2[grow];
  }

  const int ng = tid & 3, rg = (tid >> 2) & 3, ks = tid >> 4;
  float4 acc[4][8];
#pragma unroll
  for (int j = 0; j < 4; ++j)
#pragma unroll
    for (int i = 0; i < 8; ++i) acc[j][i] = make_float4(0.f, 0.f, 0.f, 0.f);

  for (int c = 0; c < 5; ++c) {
    __syncthreads();
#pragma unroll
    for (int i = 0; i < 2; ++i) {
      int f4 = i * 256 + tid;
      int rl = f4 >> 5, kq = f4 & 31;
      int g = rl >> 2, du = rl & 3;
      int grow = g * KS_ + u0 + du;
      int k = c * 128 + kq * 4;
      float4 v;
      if (k < 512) v = *(const float4*)&Wih2[grow * 512 + k];
      else         v = *(const float4*)&Whh2[grow * 128 + (k - 512)];
      *(float4*)&Wc[rl * 132 + kq * 4] = v;
    }
#pragma unroll
    for (int i = 0; i < 4; ++i) {
      int f4 = i * 256 + tid;
      int nl = f4 >> 5, kq = f4 & 31;
      int n = nbase + nl;
      int k = c * 128 + kq * 4;
      float4 v;
      if (c < 4) v = *(const float4*)&h1t[n * H_ + k];
      else       v = *(const float4*)&h2p[n * KS_ + (k - 512)];
      *(float4*)&Xs[nl * 132 + kq * 4] = v;
    }
    __syncthreads();
#pragma unroll
    for (int it = 0; it < 2; ++it) {
      int kl = (it * 16 + ks) * 4;
      float4 w[4], x[8];
#pragma unroll
      for (int j = 0; j < 4; ++j) w[j] = *(const float4*)&Wc[(rg * 4 + j) * 132 + kl];
#pragma unroll
      for (int i = 0; i < 8; ++i) x[i] = *(const float4*)&Xs[(ng + 4 * i) * 132 + kl];
#pragma unroll
      for (int j = 0; j < 4; ++j)
#pragma unroll
        for (int i = 0; i < 8; ++i) fma4(acc[j][i], w[j], x[i]);
    }
  }
#pragma unroll
  for (int j = 0; j < 4; ++j)
#pragma unroll
    for (int i = 0; i < 8; ++i)
      pp[ks * 520 + (rg * 4 + j) * 32 + ng + 4 * i] = hsum4(acc[j][i]);
  __syncthreads();
#pragma unroll
  for (int rep = 0; rep < 2; ++rep) {
    int o = rep * 256 + tid;
    float s = 0.f;
#pragma unroll
    for (int kk = 0; kk < 16; ++kk) s += pp[kk * 520 + o];
    gbuf[o] = s + bias[o >> 5];
  }
  __syncthreads();
  if (tid < 128) {
    int du = tid & 3, nl = tid >> 2;
    int n = nbase + nl, u = u0 + du;
    float ig = gbuf[(0 * 4 + du) * 32 + nl];
    float fg = gbuf[(1 * 4 + du) * 32 + nl];
    float gg = gbuf[(2 * 4 + du) * 32 + nl];
    float og = gbuf[(3 * 4 + du) * 32 + nl];
    float cn = sigm(fg) * c2[n * KS_ + u] + sigm(ig) * tanhf(gg);
    c2[n * KS_ + u] = cn;
    h2o[n * KS_ + u] = sigm(og) * tanhf(cn);
  }
}

// ---------------- attention slice partials (R3: wave-contiguous) ----------
// grid 250 x 512 threads (8 waves). WG s owns timesteps [8s, 8s+8), all 64 n.
// Wave w owns n = w*8 .. w*8+7. Per (n, row-pair): lanes 0-31 read row j
// (16 B/lane), lanes 32-63 read row j+1 -> 1 KB contiguous per instruction.
// Energy dot = 4 FMA + 5-level shfl_xor butterfly within 32-lane halves.
// pctx: lane owns v-chunk (ln&31); halves split j even/odd; xor-32 combine;
// half-wave coalesced 512 B store.
// Writes pm[n][s] (slice max), ps[n][s] (slice expsum), pctx[s][n][128].
__global__ __launch_bounds__(512, 1) void k_attn(
    const float* __restrict__ key, const float* __restrict__ values,
    const int* __restrict__ lens, const float* __restrict__ h2buf,
    float* __restrict__ pm, float* __restrict__ ps, float* __restrict__ pctx,
    int t) {
  __shared__ __align__(16) float h2s[64 * 132];
  __shared__ float es[64 * 9];
  const int tid = threadIdx.x;
  const int s = blockIdx.x;
  const int t0 = s * 8;
  const float* __restrict__ h2 = h2buf + ((t & 1) ^ 1) * (NB_ * KS_);

#pragma unroll
  for (int i = 0; i < 4; ++i) {
    int f4 = i * 512 + tid;
    int n = f4 >> 5, q = f4 & 31;
    *(float4*)&h2s[n * 132 + q * 4] = *(const float4*)&h2[n * KS_ + q * 4];
  }
  __syncthreads();

  const int wv = tid >> 6;   // wave 0..7
  const int ln = tid & 63;   // lane in wave
  const int half = ln >> 5;  // 0: lanes 0-31, 1: lanes 32-63
  const int ch = ln & 31;    // 16-B chunk index within a 512-B row

  // Phase E: energies. Wave reads rows (j, j+1) of one n per instr: 1 KB contig.
  for (int i = 0; i < 8; ++i) {
    int n = wv * 8 + i;
    float4 hc = *(const float4*)&h2s[n * 132 + ch * 4];
#pragma unroll
    for (int rp = 0; rp < 4; ++rp) {
      int j = rp * 2 + half;
      float4 kv = *(const float4*)&key[((size_t)n * TT_ + t0 + j) * KS_ + ch * 4];
      float d = kv.x * hc.x + kv.y * hc.y + kv.z * hc.z + kv.w * hc.w;
      d += __shfl_xor(d, 16);
      d += __shfl_xor(d, 8);
      d += __shfl_xor(d, 4);
      d += __shfl_xor(d, 2);
      d += __shfl_xor(d, 1);
      if (ch == 0) es[n * 9 + j] = d;
    }
  }
  __syncthreads();

  if (tid < 64) {  // per-row local softmax partials (with length mask)
    int n = tid;
    int len = lens[n];
    float ev[8];
    float m = -1e30f;
#pragma unroll
    for (int j = 0; j < 8; ++j) {
      float e = (t0 + j >= len) ? -1e9f : es[n * 9 + j];
      ev[j] = e;
      m = fmaxf(m, e);
    }
    float ssum = 0.f;
#pragma unroll
    for (int j = 0; j < 8; ++j) {
      float p = expf(ev[j] - m);
      es[n * 9 + j] = p;
      ssum += p;
    }
    pm[n * 256 + s] = m;
    ps[n * 256 + s] = ssum;
  }
  __syncthreads();

  // Phase P: partial ctx. Lane owns v-chunk ch; halves take even/odd j.
  for (int i = 0; i < 8; ++i) {
    int n = wv * 8 + i;
    float4 a = make_float4(0.f, 0.f, 0.f, 0.f);
#pragma unroll
    for (int it2 = 0; it2 < 4; ++it2) {
      int j = it2 * 2 + half;
      float p = es[n * 9 + j];
      float4 vv = *(const float4*)&values[((size_t)n * TT_ + t0 + j) * VS_ + ch * 4];
      a.x = fmaf(p, vv.x, a.x); a.y = fmaf(p, vv.y, a.y);
      a.z = fmaf(p, vv.z, a.z); a.w = fmaf(p, vv.w, a.w);
    }
    a.x += __shfl_xor(a.x, 32);
    a.y += __shfl_xor(a.y, 32);
    a.z += __shfl_xor(a.z, 32);
    a.w += __shfl_xor(a.w, 32);
    if (half == 0)
      *(float4*)&pctx[((size_t)s * 64 + n) * 128 + ch * 4] = a;
  }
}

// ---------------- finalize: combine partials, ctx, pred ----------------
// grid 64 (one WG per batch row).
__global__ __launch_bounds__(256, 1) void k_fin(
    const float* __restrict__ pm, const float* __restrict__ ps,
    const float* __restrict__ pctx, const float* __restrict__ h2buf,
    const float* __restrict__ emb, const float* __restrict__ bout,
    float* __restrict__ ctx, float* __restrict__ out, int t) {
  __shared__ float red[256];
  __shared__ float ews[256];
  __shared__ float cbuf[256];
  __shared__ float cat[256];
  const int tid = threadIdx.x;
  const int n = blockIdx.x;
  const float* __restrict__ h2 = h2buf + ((t & 1) ^ 1) * (NB_ * KS_);

  float m = -1e30f;
  if (tid < 250) m = pm[n * 256 + tid];
  red[tid] = m;
  __syncthreads();
  for (int w = 128; w > 0; w >>= 1) {
    if (tid < w) red[tid] = fmaxf(red[tid], red[tid + w]);
    __syncthreads();
  }
  float M = red[0];
  __syncthreads();
  float wv = 0.f;
  if (tid < 250) {
    float e = expf(m - M);
    ews[tid] = e;
    wv = e * ps[n * 256 + tid];
  } else {
    ews[tid] = 0.f;
  }
  red[tid] = wv;
  __syncthreads();
  for (int w = 128; w > 0; w >>= 1) {
    if (tid < w) red[tid] += red[tid + w];
    __syncthreads();
  }
  float S = red[0];
  {  // ctx accumulate: thread (v = tid&127, sh = tid>>7) over 125 slices
    int v = tid & 127, sh = tid >> 7;
    float a = 0.f;
    for (int i = 0; i < 125; ++i) {
      int sl = sh * 125 + i;
      a = fmaf(ews[sl], pctx[((size_t)sl * 64 + n) * 128 + v], a);
    }
    cbuf[sh * 128 + v] = a;
  }
  __syncthreads();
  if (tid < 128) {
    float cv = (cbuf[tid] + cbuf[128 + tid]) / S;
    ctx[n * 128 + tid] = cv;
    cat[128 + tid] = cv;
    cat[tid] = h2[n * KS_ + tid];
  }
  __syncthreads();
  if (tid < V_) {  // tied-weight pred: logits = [h2|ctx] @ emb^T + b_out
    float a = bout[tid];
    const float* er = emb + tid * E_;
#pragma unroll 8
    for (int q = 0; q < 64; ++q) {
      float4 ev = *(const float4*)&er[q * 4];
      a = fmaf(ev.x, cat[q * 4 + 0], a);
      a = fmaf(ev.y, cat[q * 4 + 1], a);
      a = fmaf(ev.z, cat[q * 4 + 2], a);
      a = fmaf(ev.w, cat[q * 4 + 3], a);
    }
    out[((size_t)n * LL_ + t) * V_ + tid] = a;
  }
}

extern "C" void kernel_launch(void* const* d_in, const int* in_sizes, int n_in,
                              void* d_out, int out_size, void* d_ws,
                              size_t ws_size, hipStream_t stream) {
  const float* key    = (const float*)d_in[0];
  const float* values = (const float*)d_in[1];
  const int*   lens   = (const int*)d_in[2];
  const int*   text   = (const int*)d_in[3];
  const float* emb    = (const float*)d_in[4];
  const float* Wih1   = (const float*)d_in[5];
  const float* Whh1   = (const float*)d_in[6];
  const float* bih1   = (const float*)d_in[7];
  const float* bhh1   = (const float*)d_in[8];
  const float* Wih2   = (const float*)d_in[9];
  const float* Whh2   = (const float*)d_in[10];
  const float* bih2   = (const float*)d_in[11];
  const float* bhh2   = (const float*)d_in[12];
  const float* bout   = (const float*)d_in[13];
  float* out = (float*)d_out;
  float* ws = (float*)d_ws;

  // workspace layout (floats):
  float* h1buf = ws;               // 2 * 64*512 = 65536
  float* c1    = ws + 65536;       // 32768
  float* h2buf = ws + 98304;       // 2 * 64*128 = 16384
  float* c2    = ws + 114688;      // 8192
  float* ctx   = ws + 122880;      // 8192   (state region ends at 131072)
  float* pm    = ws + 131072;      // 64*256 = 16384
  float* ps    = ws + 147456;      // 16384
  float* pctx  = ws + 163840;      // 250*64*128 = 2048000 (~8.9 MB total)

  hipLaunchKernelGGL(k_zero, dim3(128), dim3(256), 0, stream, ws);
  for (int t = 0; t < LL_; ++t) {
    hipLaunchKernelGGL(k_lstm1, dim3(256), dim3(256), 0, stream,
                       emb, text, Wih1, Whh1, bih1, bhh1, ctx, h1buf, c1, t);
    hipLaunchKernelGGL(k_lstm2, dim3(64), dim3(256), 0, stream,
                       Wih2, Whh2, bih2, bhh2, h1buf, h2buf, c2, t);
    hipLaunchKernelGGL(k_attn, dim3(250), dim3(512), 0, stream,
                       key, values, lens, h2buf, pm, ps, pctx, t);
    hipLaunchKernelGGL(k_fin, dim3(64), dim3(256), 0, stream,
                       pm, ps, pctx, h2buf, emb, bout, ctx, out, t);
  }
}